// Round 6
// baseline (8715.144 us; speedup 1.0000x reference)
//
#include <hip/hip_runtime.h>

#define BB 512
#define TT 512
#define DD 76
#define HH 256
#define NC 25
#define NBLK 256
#define NTH 512
#define BBHH (BB * HH)   // u32 words per h slot

#define K1 352      // L1 virtual K: 256 h1 | 76 x | 20 zero-pad (h1 first)
#define K2 512      // L2 K: 256 h1 | 256 h2
#define WS1 360     // LDS k-stride (u16) for W1 planes
#define WS2 520     // LDS k-stride (u16) for W2 planes

typedef unsigned short u16;
typedef unsigned int u32;
typedef unsigned long long u64;
typedef __attribute__((ext_vector_type(8))) short bf16x8;
typedef __attribute__((ext_vector_type(4))) float f32x4;

__device__ __forceinline__ float bf2f(u16 v) {
  union { u32 u; float f; } c; c.u = ((u32)v) << 16; return c.f;
}
__device__ __forceinline__ u16 f2bf(float f) {
  union { u32 u; float f; } c; c.f = f;
  u32 r = c.u + 0x7FFFu + ((c.u >> 16) & 1u);   // RNE
  return (u16)(r >> 16);
}
__device__ __forceinline__ void split2(float f, u16& h, u16& l) {
  u16 hh = f2bf(f);
  float r = f - bf2f(hh);
  h = hh; l = f2bf(r);
}
__device__ __forceinline__ float tanh_f(float v) {
  float e = __expf(2.0f * v);
  return 1.0f - 2.0f / (e + 1.0f);
}
__device__ __forceinline__ float gact(float v, bool is_tanh) {
  float e = __expf(is_tanh ? 2.0f * v : -v);
  float inv = 1.0f / (1.0f + e);
  return is_tanh ? 1.0f - 2.0f * inv : inv;
}

// ---- coherence-point (IF$) transport: relaxed agent atomics, NO fences ----
__device__ __forceinline__ u64 ald2(const u32* p) {
  return __hip_atomic_load((const u64*)p, __ATOMIC_RELAXED, __HIP_MEMORY_SCOPE_AGENT);
}
__device__ __forceinline__ u32 ald1(const u32* p) {
  return __hip_atomic_load(p, __ATOMIC_RELAXED, __HIP_MEMORY_SCOPE_AGENT);
}
__device__ __forceinline__ void ast1(u32* p, u32 v) {
  __hip_atomic_store(p, v, __ATOMIC_RELAXED, __HIP_MEMORY_SCOPE_AGENT);
}
__device__ __forceinline__ void ast2(u64* p, u64 v) {
  __hip_atomic_store(p, v, __ATOMIC_RELAXED, __HIP_MEMORY_SCOPE_AGENT);
}

// ---- per-WAVE flag sync (no block barriers in main loop) ----
// wait: lanes 0..31 poll 32 slots (one per jt block of this (bt,m) cohort)
__device__ __forceinline__ void wwait32(const u32* base, u32 target) {
  if ((threadIdx.x & 63) < 32) {
    const u32* p = base + (threadIdx.x & 63) * 16;
    while (__hip_atomic_load(p, __ATOMIC_RELAXED, __HIP_MEMORY_SCOPE_AGENT) < target)
      __builtin_amdgcn_s_sleep(1);
  }
  asm volatile("" ::: "memory");   // pin subsequent h loads after the poll
}
// post: drain this wave's h-stores to the coherence point, then flag
__device__ __forceinline__ void wpost(u32* slot, u32 val) {
  asm volatile("s_waitcnt vmcnt(0)" ::: "memory");
  if ((threadIdx.x & 63) == 0) ast1(slot, val);
}

// packed h word: low16 = bf16-hi part, high16 = bf16-lo part
__device__ __forceinline__ bf16x8 hi8(const u64 w[4]) {
  union { u32 u[4]; bf16x8 v; } c;
#pragma unroll
  for (int i = 0; i < 4; ++i)
    c.u[i] = __builtin_amdgcn_perm((u32)(w[i] >> 32), (u32)w[i], 0x05040100u);
  return c.v;
}
__device__ __forceinline__ bf16x8 lo8(const u64 w[4]) {
  union { u32 u[4]; bf16x8 v; } c;
#pragma unroll
  for (int i = 0; i < 4; ++i)
    c.u[i] = __builtin_amdgcn_perm((u32)(w[i] >> 32), (u32)w[i], 0x07060302u);
  return c.v;
}

__device__ __forceinline__ void splitv8(const float* f, bf16x8& vh, bf16x8& vl) {
  union { u16 s[8]; bf16x8 v; } ch, cl;
#pragma unroll
  for (int i = 0; i < 8; ++i) { u16 h_, l_; split2(f[i], h_, l_); ch.s[i] = h_; cl.s[i] = l_; }
  vh = ch.v; vl = cl.v;
}

// ---- repack: fp32 [k][4H] -> hi/lo bf16 planes, layout [c=4j+g][k] ----
// W1 k-order: k 0..255 = Wh1 (h1 terms first), 256..331 = Wi1, 332..351 zero
__global__ void repack_kernel(const float* __restrict__ Wi1, const float* __restrict__ Wh1,
                              const float* __restrict__ Wi2, const float* __restrict__ Wh2,
                              u16* __restrict__ w1hg, u16* __restrict__ w1lg,
                              u16* __restrict__ w2hg, u16* __restrict__ w2lg) {
  int idx = blockIdx.x * blockDim.x + threadIdx.x;
  const int N1 = 1024 * K1;
  if (idx < N1) {
    int c = idx / K1, k = idx - c * K1;
    int src = (c & 3) * HH + (c >> 2);
    float v = 0.f;
    if (k < HH) v = Wh1[k * 1024 + src];
    else if (k < HH + DD) v = Wi1[(k - HH) * 1024 + src];
    u16 h, l; split2(v, h, l);
    w1hg[idx] = h; w1lg[idx] = l;
  } else if (idx < N1 + 1024 * K2) {
    int d = idx - N1;
    int c = d >> 9, k = d & 511;
    int src = (c & 3) * HH + (c >> 2);
    float v = (k < HH) ? Wi2[k * 1024 + src] : Wh2[(k - HH) * 1024 + src];
    u16 h, l; split2(v, h, l);
    w2hg[d] = h; w2lg[d] = l;
  }
}

// one K-chunk, BOTH 16-col tiles, 3-term split-fp32 MFMA (p0h..p1l, a0A..a1C in scope)
#define MCH2(AH, AL, KOFF)                                                  \
  { bf16x8 b0h_ = *(const bf16x8*)(p0h + (KOFF));                           \
    bf16x8 b0l_ = *(const bf16x8*)(p0l + (KOFF));                           \
    bf16x8 b1h_ = *(const bf16x8*)(p1h + (KOFF));                           \
    bf16x8 b1l_ = *(const bf16x8*)(p1l + (KOFF));                           \
    a0A = __builtin_amdgcn_mfma_f32_16x16x32_bf16(AH, b0h_, a0A, 0, 0, 0);  \
    a0B = __builtin_amdgcn_mfma_f32_16x16x32_bf16(AH, b0l_, a0B, 0, 0, 0);  \
    a0C = __builtin_amdgcn_mfma_f32_16x16x32_bf16(AL, b0h_, a0C, 0, 0, 0);  \
    a1A = __builtin_amdgcn_mfma_f32_16x16x32_bf16(AH, b1h_, a1A, 0, 0, 0);  \
    a1B = __builtin_amdgcn_mfma_f32_16x16x32_bf16(AH, b1l_, a1B, 0, 0, 0);  \
    a1C = __builtin_amdgcn_mfma_f32_16x16x32_bf16(AL, b1h_, a1C, 0, 0, 0); }

// gates for both tiles + coalesced 32B/row store (this wave's OWN 16 rows)
#define GATES2T(Z0, Z1, CS0, CS1, DST)                                      \
  { u32 g0v[4], g1v[4];                                                     \
    _Pragma("unroll")                                                       \
    for (int r = 0; r < 4; ++r) {                                           \
      float a0_ = gact((Z0)[r], gi == 2);                                   \
      float p01 = __shfl_xor(a0_, 1), p02 = __shfl_xor(a0_, 2), p03 = __shfl_xor(a0_, 3); \
      float c0_ = p01 * (CS0)[r] + a0_ * p02;                               \
      (CS0)[r] = c0_;                                                       \
      float h0_ = p03 * tanh_f(c0_);                                        \
      u16 hh0_, hl0_; split2(h0_, hh0_, hl0_);                              \
      g0v[r] = (u32)hh0_ | ((u32)hl0_ << 16);                               \
      float a1_ = gact((Z1)[r], gi == 2);                                   \
      float p11 = __shfl_xor(a1_, 1), p12 = __shfl_xor(a1_, 2), p13 = __shfl_xor(a1_, 3); \
      float c1_ = p11 * (CS1)[r] + a1_ * p12;                               \
      (CS1)[r] = c1_;                                                       \
      float h1_ = p13 * tanh_f(c1_);                                        \
      u16 hh1_, hl1_; split2(h1_, hh1_, hl1_);                              \
      g1v[r] = (u32)hh1_ | ((u32)hl1_ << 16);                               \
    }                                                                       \
    _Pragma("unroll")                                                       \
    for (int r = 0; r < 4; ++r) {                                           \
      int base_ = lane & 48;                                                \
      u32 a1_ = __shfl(g0v[r], base_ + 4);                                  \
      u32 a2_ = __shfl(g0v[r], base_ + 8);                                  \
      u32 a3_ = __shfl(g0v[r], base_ + 12);                                 \
      u32 b1_ = __shfl(g1v[r], base_ + 4);                                  \
      u32 b2_ = __shfl(g1v[r], base_ + 8);                                  \
      u32 b3_ = __shfl(g1v[r], base_ + 12);                                 \
      if (nl == 0) {                                                        \
        u64* dp_ = (u64*)((DST) + (size_t)(rbase + r) * HH + jt * 8);       \
        ast2(dp_,     (u64)g0v[r] | ((u64)a1_ << 32));                      \
        ast2(dp_ + 1, (u64)a2_    | ((u64)a3_ << 32));                      \
        ast2(dp_ + 2, (u64)g1v[r] | ((u64)b1_ << 32));                      \
        ast2(dp_ + 3, (u64)b2_    | ((u64)b3_ << 32));                      \
      }                                                                     \
    }                                                                       \
  }

// full-K packed-h load: 8 chunks x 4 u64 per lane (32B/lane/chunk, coalesced)
#define LOAD_RW8(RW, BASEPTR)                                               \
  { const u32* hp_ = (BASEPTR) + (size_t)arow * HH;                         \
    _Pragma("unroll")                                                       \
    for (int i_ = 0; i_ < 8; ++i_) {                                        \
      const u32* p_ = hp_ + i_ * 32 + qd * 8;                               \
      (RW)[i_][0] = ald2(p_);     (RW)[i_][1] = ald2(p_ + 2);               \
      (RW)[i_][2] = ald2(p_ + 4); (RW)[i_][3] = ald2(p_ + 6);               \
    } }

// x row: chunks 8,9 full 32-wide, chunk 10 = cols 64..75 + zero pad
#define X_LOAD(XROW)                                                        \
    float4 xa0 = *(const float4*)((XROW) + qd * 8);                         \
    float4 xa1 = *(const float4*)((XROW) + qd * 8 + 4);                     \
    float4 xb0 = *(const float4*)((XROW) + 32 + qd * 8);                    \
    float4 xb1 = *(const float4*)((XROW) + 32 + qd * 8 + 4);                \
    float4 xc0 = make_float4(0,0,0,0), xc1 = make_float4(0,0,0,0);          \
    if (qd == 0) { xc0 = *(const float4*)((XROW) + 64);                     \
                   xc1 = *(const float4*)((XROW) + 68); }                   \
    else if (qd == 1) { xc0 = *(const float4*)((XROW) + 72); }

#define X_MFMA2()                                                           \
  { float xv[8]; bf16x8 xh, xl;                                             \
    xv[0]=xa0.x; xv[1]=xa0.y; xv[2]=xa0.z; xv[3]=xa0.w;                     \
    xv[4]=xa1.x; xv[5]=xa1.y; xv[6]=xa1.z; xv[7]=xa1.w;                     \
    splitv8(xv, xh, xl); MCH2(xh, xl, 8 * 32 + qd * 8)                      \
    xv[0]=xb0.x; xv[1]=xb0.y; xv[2]=xb0.z; xv[3]=xb0.w;                     \
    xv[4]=xb1.x; xv[5]=xb1.y; xv[6]=xb1.z; xv[7]=xb1.w;                     \
    splitv8(xv, xh, xl); MCH2(xh, xl, 9 * 32 + qd * 8)                      \
    xv[0]=xc0.x; xv[1]=xc0.y; xv[2]=xc0.z; xv[3]=xc0.w;                     \
    xv[4]=xc1.x; xv[5]=xc1.y; xv[6]=xc1.z; xv[7]=xc1.w;                     \
    splitv8(xv, xh, xl); MCH2(xh, xl, 10 * 32 + qd * 8) }

__global__ __launch_bounds__(NTH) void lstm_kernel(
    const float* __restrict__ x,
    const float* __restrict__ b1, const float* __restrict__ b2,
    const float* __restrict__ Wd, const float* __restrict__ bd,
    const u16* __restrict__ w1hg, const u16* __restrict__ w1lg,
    const u16* __restrict__ w2hg, const u16* __restrict__ w2lg,
    u32* __restrict__ h1w, u32* __restrict__ h2w,
    u32* __restrict__ flags,
    float* __restrict__ out)
{
  __shared__ u16 w1h[32 * WS1], w1l[32 * WS1];     // 46,080 B
  __shared__ u16 w2h[32 * WS2], w2l[32 * WS2];     // 66,560 B  (112,640 total)

  const int tid = threadIdx.x;
  const int lane = tid & 63;
  const int wv = tid >> 6;            // 0..7
  const int m  = wv & 3;              // row-group: rows m*16..m*16+15
  const int grp = wv >> 2;            // 0 = L1 wave, 1 = L2 wave
  const int nl = lane & 15;
  const int qd = lane >> 4;           // 0..3
  const int bt = blockIdx.x & 7;      // row block (64 rows)
  const int jt = blockIdx.x >> 3;     // 0..31 col-group (32 cols)
  const int row0 = bt * 64;

  // ---- stage weight slices (32 cols) to LDS once — the ONLY block barrier ----
  for (int i = tid; i < 32 * (K1 / 2); i += NTH) {
    int c = i / 176, kk = i - c * 176;
    ((u32*)&w1h[c * WS1])[kk] = ((const u32*)(w1hg + (size_t)(jt * 32 + c) * K1))[kk];
    ((u32*)&w1l[c * WS1])[kk] = ((const u32*)(w1lg + (size_t)(jt * 32 + c) * K1))[kk];
  }
  for (int i = tid; i < 32 * (K2 / 2); i += NTH) {
    int c = i >> 8, kk = i & 255;
    ((u32*)&w2h[c * WS2])[kk] = ((const u32*)(w2hg + (size_t)(jt * 32 + c) * K2))[kk];
    ((u32*)&w2l[c * WS2])[kk] = ((const u32*)(w2lg + (size_t)(jt * 32 + c) * K2))[kk];
  }
  __syncthreads();

  const int gi = nl & 3;                      // gate index of this lane's cols
  const int rbase = row0 + m * 16 + qd * 4;   // gate-output rows
  const int arow = row0 + m * 16 + nl;        // A-fragment row

  // per-(bt,m) flag cohorts: 32 slots (one per jt), 64B spacing
  u32* fA = flags;                   // h2 flags: posted = t+1 after h2[t]
  u32* fB = flags + 16384;           // h1 flags: posted = i+1 after h1[i]
  u32* fAm = fA + (bt * 4 + m) * 512;
  u32* fBm = fB + (bt * 4 + m) * 512;
  u32* fAslot = fAm + jt * 16;
  u32* fBslot = fBm + jt * 16;

  if (grp == 0) {
    // =========================== L1 wave ===========================
    const u16* p0h = w1h + nl * WS1;
    const u16* p0l = w1l + nl * WS1;
    const u16* p1h = w1h + (16 + nl) * WS1;
    const u16* p1l = w1l + (16 + nl) * WS1;
    const float ab0 = b1[gi * HH + ((jt * 32 + nl) >> 2)];
    const float ab1v = b1[gi * HH + ((jt * 32 + 16 + nl) >> 2)];
    float cs0[4] = {0.f, 0.f, 0.f, 0.f}, cs1[4] = {0.f, 0.f, 0.f, 0.f};
    u64 rw[8][4];

#pragma unroll 1
    for (int i = 0; i < TT; ++i) {
      const float* xrow = x + ((size_t)arow * TT + i) * DD;
      X_LOAD(xrow)                               // x loads fly during flag waits
      if (i > 0) {
        wwait32(fBm, (u32)i);                    // h1[i-1] published by all jt
        LOAD_RW8(rw, h1w + (size_t)((i - 1) & 3) * BBHH)
      }
      if (i >= 4) wwait32(fAm, (u32)(i - 3));    // back-pressure: L2 consumed h1[i-4]
      f32x4 a0A = {ab0, ab0, ab0, ab0}, a1A = {ab1v, ab1v, ab1v, ab1v};
      f32x4 a0B = {0,0,0,0}, a0C = {0,0,0,0}, a1B = {0,0,0,0}, a1C = {0,0,0,0};
      if (i > 0) {
#pragma unroll
        for (int c = 0; c < 8; ++c) {
          bf16x8 ah = hi8(rw[c]), al = lo8(rw[c]);
          MCH2(ah, al, c * 32 + qd * 8)
        }
      }
      X_MFMA2()
      f32x4 z0 = a0A + a0B + a0C, z1 = a1A + a1B + a1C;
      GATES2T(z0, z1, cs0, cs1, h1w + (size_t)(i & 3) * BBHH)
      wpost(fBslot, (u32)(i + 1));
    }
  } else {
    // =========================== L2 wave ===========================
    const u16* p0h = w2h + nl * WS2;
    const u16* p0l = w2l + nl * WS2;
    const u16* p1h = w2h + (16 + nl) * WS2;
    const u16* p1l = w2l + (16 + nl) * WS2;
    const float ab0 = b2[gi * HH + ((jt * 32 + nl) >> 2)];
    const float ab1v = b2[gi * HH + ((jt * 32 + 16 + nl) >> 2)];
    float cs0[4] = {0.f, 0.f, 0.f, 0.f}, cs1[4] = {0.f, 0.f, 0.f, 0.f};
    u64 rh1[8][4], rh2[8][4];

#pragma unroll 1
    for (int t = 0; t < TT; ++t) {
      wwait32(fBm, (u32)(t + 1));                // h1[t] ready
      LOAD_RW8(rh1, h1w + (size_t)(t & 3) * BBHH)
      if (t > 0) {
        wwait32(fAm, (u32)t);                    // h2[t-1] ready; h2[t] slot write-safe
        LOAD_RW8(rh2, h2w + (size_t)((t - 1) & 1) * BBHH)
      }
      f32x4 a0A = {ab0, ab0, ab0, ab0}, a1A = {ab1v, ab1v, ab1v, ab1v};
      f32x4 a0B = {0,0,0,0}, a0C = {0,0,0,0}, a1B = {0,0,0,0}, a1C = {0,0,0,0};
#pragma unroll
      for (int c = 0; c < 8; ++c) {              // h1 terms (Wi2) — covers rh2 flight
        bf16x8 ah = hi8(rh1[c]), al = lo8(rh1[c]);
        MCH2(ah, al, c * 32 + qd * 8)
      }
      if (t > 0) {
#pragma unroll
        for (int c = 0; c < 8; ++c) {            // h2 terms (Wh2)
          bf16x8 ah = hi8(rh2[c]), al = lo8(rh2[c]);
          MCH2(ah, al, (8 + c) * 32 + qd * 8)
        }
      }
      f32x4 z0 = a0A + a0B + a0C, z1 = a1A + a1B + a1C;
      GATES2T(z0, z1, cs0, cs1, h2w + (size_t)(t & 1) * BBHH)
      wpost(fAslot, (u32)(t + 1));
    }

    // ---- dense head (wave 4 only): rows row0+jt*2, +1 of h2[511] (slot 1) ----
    if (wv == 4) {
      const int mh = jt >> 3;                    // row-group of the head rows
      wwait32(fA + (bt * 4 + mh) * 512, (u32)TT);
      if (lane < 2 * NC) {
        int r = row0 + jt * 2 + lane / NC;
        int n = lane - (lane / NC) * NC;
        float s = bd[n];
        const u32* fw = h2w + BBHH + (size_t)r * HH;
#pragma unroll 8
        for (int k = 0; k < HH; ++k) {
          u32 w = ald1(fw + k);
          s += (bf2f((u16)w) + bf2f((u16)(w >> 16))) * Wd[k * NC + n];
        }
        out[r * NC + n] = s;
      }
    }
  }
}

extern "C" void kernel_launch(void* const* d_in, const int* in_sizes, int n_in,
                              void* d_out, int out_size, void* d_ws, size_t ws_size,
                              hipStream_t stream) {
  const float* x   = (const float*)d_in[0];
  const float* Wi1 = (const float*)d_in[1];
  const float* Wh1 = (const float*)d_in[2];
  const float* b1  = (const float*)d_in[3];
  const float* Wi2 = (const float*)d_in[4];
  const float* Wh2 = (const float*)d_in[5];
  const float* b2  = (const float*)d_in[6];
  const float* Wd  = (const float*)d_in[7];
  const float* bd  = (const float*)d_in[8];

  char* ws = (char*)d_ws;
  // ws layout (bytes), total 6,815,744:
  //   [0, 2M)              h1w 4-deep u32 words (hi|lo<<16) [4][512][256]
  //   [2M, 3M)             h2w 2-deep [2][512][256]
  //   [3,145,728 ..)       w1hg/w1lg (720,896 each), w2hg/w2lg (1,048,576 each)
  //   [6,684,672, +128K)   flag arrays fA, fB (zeroed every call)
  u32* h1w = (u32*)(ws);
  u32* h2w = (u32*)(ws + 2097152u);
  u16* w1hg = (u16*)(ws + 3145728u);
  u16* w1lg = (u16*)(ws + 3145728u + 720896u);
  u16* w2hg = (u16*)(ws + 3145728u + 2u * 720896u);
  u16* w2lg = (u16*)(ws + 3145728u + 2u * 720896u + 1048576u);
  u32* flags = (u32*)(ws + 6684672u);
  float* out = (float*)d_out;

  hipMemsetAsync((void*)flags, 0, 131072, stream);
  const int total = 1024 * K1 + 1024 * K2;
  repack_kernel<<<(total + 255) / 256, 256, 0, stream>>>(
      Wi1, Wh1, Wi2, Wh2, w1hg, w1lg, w2hg, w2lg);

  void* args[] = {
    (void*)&x, (void*)&b1, (void*)&b2, (void*)&Wd, (void*)&bd,
    (void*)&w1hg, (void*)&w1lg, (void*)&w2hg, (void*)&w2lg,
    (void*)&h1w, (void*)&h2w,
    (void*)&flags, (void*)&out
  };
  // Cooperative launch purely for co-residency; 256 blocks x 512 thr = 1 block/CU.
  (void)hipLaunchCooperativeKernel((void*)lstm_kernel, dim3(NBLK),
                                   dim3(NTH), args, 0, stream);
}

// Round 8
// 5480.542 us; speedup vs baseline: 1.5902x; 1.5902x over previous
//
#include <hip/hip_runtime.h>

#define BB 512
#define TT 512
#define DD 76
#define HH 256
#define NC 25
#define NBLK 256
#define NTHREADS 512
#define BBHH (BB * HH)   // u32 words per h slot

#define K1 352      // L1 virtual K: 256 h1 | 76 x | 20 zero-pad (h1 first)
#define K2 512      // L2 K: 256 h1 | 256 h2
#define WS1 360     // LDS k-stride (u16) for W1 planes
#define WS2 520     // LDS k-stride (u16) for W2 planes

typedef unsigned short u16;
typedef unsigned int u32;
typedef unsigned long long u64;
typedef __attribute__((ext_vector_type(8))) short bf16x8;
typedef __attribute__((ext_vector_type(4))) float f32x4;

__device__ __forceinline__ float bf2f(u16 v) {
  union { u32 u; float f; } c; c.u = ((u32)v) << 16; return c.f;
}
__device__ __forceinline__ u16 f2bf(float f) {
  union { u32 u; float f; } c; c.f = f;
  u32 r = c.u + 0x7FFFu + ((c.u >> 16) & 1u);   // RNE
  return (u16)(r >> 16);
}
__device__ __forceinline__ void split2(float f, u16& h, u16& l) {
  u16 hh = f2bf(f);
  float r = f - bf2f(hh);
  h = hh; l = f2bf(r);
}
__device__ __forceinline__ float tanh_f(float v) {
  float e = __expf(2.0f * v);
  return 1.0f - 2.0f / (e + 1.0f);
}
__device__ __forceinline__ float gact(float v, bool is_tanh) {
  float e = __expf(is_tanh ? 2.0f * v : -v);
  float inv = 1.0f / (1.0f + e);
  return is_tanh ? 1.0f - 2.0f * inv : inv;
}

// ---- coherence-point (IF$) transport: relaxed agent atomics, NO fences ----
__device__ __forceinline__ u64 ald2(const u32* p) {
  return __hip_atomic_load((const u64*)p, __ATOMIC_RELAXED, __HIP_MEMORY_SCOPE_AGENT);
}
__device__ __forceinline__ u32 ald1(const u32* p) {
  return __hip_atomic_load(p, __ATOMIC_RELAXED, __HIP_MEMORY_SCOPE_AGENT);
}
__device__ __forceinline__ void ast1(u32* p, u32 v) {
  __hip_atomic_store(p, v, __ATOMIC_RELAXED, __HIP_MEMORY_SCOPE_AGENT);
}
__device__ __forceinline__ void ast2(u64* p, u64 v) {
  __hip_atomic_store(p, v, __ATOMIC_RELAXED, __HIP_MEMORY_SCOPE_AGENT);
}

// ---- distributed flag sync: 32 flags/cohort, each on own 128B line ----
__device__ __forceinline__ void wait_flags(const u32* fbase, u32 target) {
  if (threadIdx.x < 32) {
    const u32* p = fbase + threadIdx.x * 32;
    while (__hip_atomic_load(p, __ATOMIC_RELAXED, __HIP_MEMORY_SCOPE_AGENT) < target)
      __builtin_amdgcn_s_sleep(1);
  }
  __syncthreads();   // execution-orders subsequent h loads after the poll
}
__device__ __forceinline__ void post_flag(u32* slot, u32 val) {
  __syncthreads();   // all waves' h-stores vmcnt-drained (at coherence point)
  if (threadIdx.x == 0) ast1(slot, val);
}

// packed h word: low16 = bf16-hi part, high16 = bf16-lo part
__device__ __forceinline__ bf16x8 hi8(const u64 w[4]) {
  union { u32 u[4]; bf16x8 v; } c;
#pragma unroll
  for (int i = 0; i < 4; ++i)
    c.u[i] = __builtin_amdgcn_perm((u32)(w[i] >> 32), (u32)w[i], 0x05040100u);
  return c.v;
}
__device__ __forceinline__ bf16x8 lo8(const u64 w[4]) {
  union { u32 u[4]; bf16x8 v; } c;
#pragma unroll
  for (int i = 0; i < 4; ++i)
    c.u[i] = __builtin_amdgcn_perm((u32)(w[i] >> 32), (u32)w[i], 0x07060302u);
  return c.v;
}

__device__ __forceinline__ void splitv8(const float* f, bf16x8& vh, bf16x8& vl) {
  union { u16 s[8]; bf16x8 v; } ch, cl;
#pragma unroll
  for (int i = 0; i < 8; ++i) { u16 h_, l_; split2(f[i], h_, l_); ch.s[i] = h_; cl.s[i] = l_; }
  vh = ch.v; vl = cl.v;
}

// ---- repack: fp32 [k][4H] -> hi/lo bf16 planes, layout [c=4j+g][k] ----
// W1 k-order: k 0..255 = Wh1 (h1 terms first), 256..331 = Wi1, 332..351 zero
__global__ void repack_kernel(const float* __restrict__ Wi1, const float* __restrict__ Wh1,
                              const float* __restrict__ Wi2, const float* __restrict__ Wh2,
                              u16* __restrict__ w1hg, u16* __restrict__ w1lg,
                              u16* __restrict__ w2hg, u16* __restrict__ w2lg) {
  int idx = blockIdx.x * blockDim.x + threadIdx.x;
  const int N1 = 1024 * K1;
  if (idx < N1) {
    int c = idx / K1, k = idx - c * K1;
    int src = (c & 3) * HH + (c >> 2);
    float v = 0.f;
    if (k < HH) v = Wh1[k * 1024 + src];
    else if (k < HH + DD) v = Wi1[(k - HH) * 1024 + src];
    u16 h, l; split2(v, h, l);
    w1hg[idx] = h; w1lg[idx] = l;
  } else if (idx < N1 + 1024 * K2) {
    int d = idx - N1;
    int c = d >> 9, k = d & 511;
    int src = (c & 3) * HH + (c >> 2);
    float v = (k < HH) ? Wi2[k * 1024 + src] : Wh2[(k - HH) * 1024 + src];
    u16 h, l; split2(v, h, l);
    w2hg[d] = h; w2lg[d] = l;
  }
}

// 3-term split-fp32 MFMA over one K-chunk, both 16-col tiles, named accs
#define MFMA_CH6(AH, AL, PH0, PL0, PH1, PL1, KOFF, A0, B0, C0, A1, B1, C1)  \
  { bf16x8 b0h_ = *(const bf16x8*)((PH0) + (KOFF));                         \
    bf16x8 b0l_ = *(const bf16x8*)((PL0) + (KOFF));                         \
    bf16x8 b1h_ = *(const bf16x8*)((PH1) + (KOFF));                         \
    bf16x8 b1l_ = *(const bf16x8*)((PL1) + (KOFF));                         \
    A0 = __builtin_amdgcn_mfma_f32_16x16x32_bf16(AH, b0h_, A0, 0, 0, 0);    \
    B0 = __builtin_amdgcn_mfma_f32_16x16x32_bf16(AH, b0l_, B0, 0, 0, 0);    \
    C0 = __builtin_amdgcn_mfma_f32_16x16x32_bf16(AL, b0h_, C0, 0, 0, 0);    \
    A1 = __builtin_amdgcn_mfma_f32_16x16x32_bf16(AH, b1h_, A1, 0, 0, 0);    \
    B1 = __builtin_amdgcn_mfma_f32_16x16x32_bf16(AH, b1l_, B1, 0, 0, 0);    \
    C1 = __builtin_amdgcn_mfma_f32_16x16x32_bf16(AL, b1h_, C1, 0, 0, 0); }

// de-redundified gates + coalesced 16B/row store (lane nl==0 of each qd-quad)
#define GATES_ST(Z, CS, DST)                                                \
  { u32 hwv[4];                                                             \
    _Pragma("unroll")                                                       \
    for (int r = 0; r < 4; ++r) {                                           \
      float a_ = gact((Z)[r], gi == 2);                                     \
      float v1_ = __shfl_xor(a_, 1);                                        \
      float v2_ = __shfl_xor(a_, 2);                                        \
      float v3_ = __shfl_xor(a_, 3);                                        \
      float cn_ = v1_ * (CS)[r] + a_ * v2_;                                 \
      (CS)[r] = cn_;                                                        \
      float hv_ = v3_ * tanh_f(cn_);                                        \
      u16 hh_, hl_; split2(hv_, hh_, hl_);                                  \
      hwv[r] = (u32)hh_ | ((u32)hl_ << 16);                                 \
    }                                                                       \
    _Pragma("unroll")                                                       \
    for (int r = 0; r < 4; ++r) {                                           \
      int base_ = lane & 48;                                                \
      u32 w1_ = __shfl(hwv[r], base_ + 4);                                  \
      u32 w2_ = __shfl(hwv[r], base_ + 8);                                  \
      u32 w3_ = __shfl(hwv[r], base_ + 12);                                 \
      if (nl == 0) {                                                        \
        u64* dp_ = (u64*)((DST) + (size_t)(rbase + r) * HH + jt * 8 + kh * 4); \
        ast2(dp_,     (u64)hwv[r] | ((u64)w1_ << 32));                      \
        ast2(dp_ + 1, (u64)w2_    | ((u64)w3_ << 32));                      \
      }                                                                     \
    }                                                                       \
  }

// K-half packed-h load: 4 chunks x 4 u64 per lane (32B/lane/chunk, coalesced)
#define LOAD_RW(RW, BASEPTR)                                                \
  { const u32* hp_ = (BASEPTR) + (size_t)arow * HH + kh * 128;              \
    _Pragma("unroll")                                                       \
    for (int i_ = 0; i_ < 4; ++i_) {                                        \
      const u32* p_ = hp_ + i_ * 32 + qd * 8;                               \
      (RW)[i_][0] = ald2(p_);     (RW)[i_][1] = ald2(p_ + 2);               \
      (RW)[i_][2] = ald2(p_ + 4); (RW)[i_][3] = ald2(p_ + 6);               \
    } }

__global__ __launch_bounds__(NTHREADS) void lstm_kernel(
    const float* __restrict__ x,
    const float* __restrict__ b1, const float* __restrict__ b2,
    const float* __restrict__ Wd, const float* __restrict__ bd,
    const u16* __restrict__ w1hg, const u16* __restrict__ w1lg,
    const u16* __restrict__ w2hg, const u16* __restrict__ w2lg,
    u32* __restrict__ h1w, u32* __restrict__ h2w,
    u32* __restrict__ flags,
    float* __restrict__ out)
{
  __shared__ u16 w1h[32 * WS1], w1l[32 * WS1];     // 46,080 B
  __shared__ u16 w2h[32 * WS2], w2l[32 * WS2];     // 66,560 B
  __shared__ float zx[2][8][64][4];                // 16,384 B (z exchange)

  const int tid = threadIdx.x;
  const int lane = tid & 63;
  const int wv = tid >> 6;            // 0..7
  const int m  = wv & 3;              // row-group: rows m*16..m*16+15
  const int kh = wv >> 2;             // K-half (0/1); also this wave's gate tile
  const int nl = lane & 15;
  const int qd = lane >> 4;           // 0..3
  const int bt = blockIdx.x & 7;
  const int jt = blockIdx.x >> 3;     // 0..31 col-group
  const int row0 = bt * 64;

  // single fused flag per step: value t+2 posted at end of step t (prologue posts 1)
  u32* fCp = flags + bt * 1024;
  u32* fCslot = fCp + jt * 32;

  // ---- stage weight slices to LDS once ----
  for (int i = tid; i < 32 * (K1 / 2); i += NTHREADS) {
    int c = i / 176, kk = i - c * 176;
    ((u32*)&w1h[c * WS1])[kk] = ((const u32*)(w1hg + (size_t)(jt * 32 + c) * K1))[kk];
    ((u32*)&w1l[c * WS1])[kk] = ((const u32*)(w1lg + (size_t)(jt * 32 + c) * K1))[kk];
  }
  for (int i = tid; i < 32 * (K2 / 2); i += NTHREADS) {
    int c = i >> 8, kk = i & 255;
    ((u32*)&w2h[c * WS2])[kk] = ((const u32*)(w2hg + (size_t)(jt * 32 + c) * K2))[kk];
    ((u32*)&w2l[c * WS2])[kk] = ((const u32*)(w2lg + (size_t)(jt * 32 + c) * K2))[kk];
  }

  const int cg_col = jt * 32 + kh * 16 + nl;
  const int gi = cg_col & 3;
  const int rbase = row0 + m * 16 + qd * 4;
  const int arow = row0 + m * 16 + nl;

  float ab1[2], ab2[2];
#pragma unroll
  for (int tl = 0; tl < 2; ++tl) {
    int col = jt * 32 + tl * 16 + nl;
    float v1 = b1[(col & 3) * HH + (col >> 2)];
    float v2 = b2[(col & 3) * HH + (col >> 2)];
    ab1[tl] = (kh == 0) ? v1 : 0.f;
    ab2[tl] = (kh == 0) ? v2 : 0.f;
  }

  const u16* pB1h0 = w1h + nl * WS1;
  const u16* pB1l0 = w1l + nl * WS1;
  const u16* pB1h1 = w1h + (16 + nl) * WS1;
  const u16* pB1l1 = w1l + (16 + nl) * WS1;
  const u16* pB2h0 = w2h + nl * WS2;
  const u16* pB2l0 = w2l + nl * WS2;
  const u16* pB2h1 = w2h + (16 + nl) * WS2;
  const u16* pB2l1 = w2l + (16 + nl) * WS2;

  float cs1[4] = {0.f, 0.f, 0.f, 0.f}, cs2[4] = {0.f, 0.f, 0.f, 0.f};
  u64 rwh1[4][4], rw2[4][4];

  __syncthreads();   // weights staged

  // ---- prologue: h1[0] = gates(b1 + x[0]@Wi1) -> slot 0; post flag=1 ----
  {
    f32x4 aA0 = {ab1[0], ab1[0], ab1[0], ab1[0]};
    f32x4 aA1 = {ab1[1], ab1[1], ab1[1], ab1[1]};
    f32x4 aB0 = {0,0,0,0}, aB1 = {0,0,0,0}, aC0 = {0,0,0,0}, aC1 = {0,0,0,0};
    const float* xrow = x + (size_t)arow * TT * DD;
    if (kh == 0) {
#pragma unroll
      for (int ci = 0; ci < 2; ++ci) {
        float xv[8];
        float4 f0 = *(const float4*)(xrow + ci * 32 + qd * 8);
        float4 f1 = *(const float4*)(xrow + ci * 32 + qd * 8 + 4);
        xv[0]=f0.x; xv[1]=f0.y; xv[2]=f0.z; xv[3]=f0.w;
        xv[4]=f1.x; xv[5]=f1.y; xv[6]=f1.z; xv[7]=f1.w;
        bf16x8 xh, xl; splitv8(xv, xh, xl);
        const int koff = (8 + ci) * 32 + qd * 8;
        MFMA_CH6(xh, xl, pB1h0, pB1l0, pB1h1, pB1l1, koff, aA0, aB0, aC0, aA1, aB1, aC1)
      }
    } else {
      float xv[8] = {0,0,0,0,0,0,0,0};
      if (qd == 0) {
        float4 f0 = *(const float4*)(xrow + 64);
        float4 f1 = *(const float4*)(xrow + 68);
        xv[0]=f0.x; xv[1]=f0.y; xv[2]=f0.z; xv[3]=f0.w;
        xv[4]=f1.x; xv[5]=f1.y; xv[6]=f1.z; xv[7]=f1.w;
      } else if (qd == 1) {
        float4 f0 = *(const float4*)(xrow + 72);
        xv[0]=f0.x; xv[1]=f0.y; xv[2]=f0.z; xv[3]=f0.w;
      }
      bf16x8 xh, xl; splitv8(xv, xh, xl);
      const int koff = 10 * 32 + qd * 8;
      MFMA_CH6(xh, xl, pB1h0, pB1l0, pB1h1, pB1l1, koff, aA0, aB0, aC0, aA1, aB1, aC1)
    }
    f32x4 zk = (kh == 0) ? (aA0 + aB0 + aC0) : (aA1 + aB1 + aC1);
    f32x4 zo = (kh == 0) ? (aA1 + aB1 + aC1) : (aA0 + aB0 + aC0);
    *(f32x4*)&zx[1][wv][lane][0] = zo;
    __syncthreads();
    zk += *(const f32x4*)&zx[1][wv ^ 4][lane][0];
    GATES_ST(zk, cs1, h1w)
    post_flag(fCslot, 1u);     // h1[0] published
  }

  // ---- main loop: fused step t = {L1[t+1] + L2[t]}, ONE rendezvous ----
#pragma unroll 1
  for (int t = 0; t < TT; ++t) {
    const u32* h1cw = h1w + (t & 1) * BBHH;        // h1[t]
    u32* h1nw = h1w + ((t + 1) & 1) * BBHH;        // h1[t+1]
    const u32* h2pw = h2w + ((t + 1) & 1) * BBHH;  // h2[t-1]
    u32* h2cw = h2w + (t & 1) * BBHH;              // h2[t]
    const bool doA = (t < TT - 1);

    // L1 accs (a*), L2 accs (b*)
    f32x4 aA0 = {ab1[0], ab1[0], ab1[0], ab1[0]};
    f32x4 aA1 = {ab1[1], ab1[1], ab1[1], ab1[1]};
    f32x4 aB0 = {0,0,0,0}, aB1 = {0,0,0,0}, aC0 = {0,0,0,0}, aC1 = {0,0,0,0};
    f32x4 bA0 = {ab2[0], ab2[0], ab2[0], ab2[0]};
    f32x4 bA1 = {ab2[1], ab2[1], ab2[1], ab2[1]};
    f32x4 bB0 = {0,0,0,0}, bB1 = {0,0,0,0}, bC0 = {0,0,0,0}, bC1 = {0,0,0,0};

    // x[t+1] loads: independent of the rendezvous — issue first
    float4 xf0, xf1, xf2, xf3;
    if (doA) {
      const float* xrow = x + ((size_t)arow * TT + (t + 1)) * DD;
      if (kh == 0) {
        xf0 = *(const float4*)(xrow + qd * 8);
        xf1 = *(const float4*)(xrow + qd * 8 + 4);
        xf2 = *(const float4*)(xrow + 32 + qd * 8);
        xf3 = *(const float4*)(xrow + 32 + qd * 8 + 4);
      } else {
        xf0 = make_float4(0,0,0,0); xf1 = make_float4(0,0,0,0);
        if (qd == 0) {
          xf0 = *(const float4*)(xrow + 64);
          xf1 = *(const float4*)(xrow + 68);
        } else if (qd == 1) {
          xf0 = *(const float4*)(xrow + 72);
        }
      }
    }

    // ---- the single rendezvous: everything step t needs is published ----
    wait_flags(fCp, (u32)(t + 1));

    // issue all h fragment loads (consumed after x-term MFMAs cover the flight)
    LOAD_RW(rwh1, h1cw)
    if (t > 0) LOAD_RW(rw2, h2pw)

    // x terms (L1) first — data long since landed
    if (doA) {
      float xv[8]; bf16x8 xh, xl;
      if (kh == 0) {
        xv[0]=xf0.x; xv[1]=xf0.y; xv[2]=xf0.z; xv[3]=xf0.w;
        xv[4]=xf1.x; xv[5]=xf1.y; xv[6]=xf1.z; xv[7]=xf1.w;
        splitv8(xv, xh, xl);
        MFMA_CH6(xh, xl, pB1h0, pB1l0, pB1h1, pB1l1, 8 * 32 + qd * 8,
                 aA0, aB0, aC0, aA1, aB1, aC1)
        xv[0]=xf2.x; xv[1]=xf2.y; xv[2]=xf2.z; xv[3]=xf2.w;
        xv[4]=xf3.x; xv[5]=xf3.y; xv[6]=xf3.z; xv[7]=xf3.w;
        splitv8(xv, xh, xl);
        MFMA_CH6(xh, xl, pB1h0, pB1l0, pB1h1, pB1l1, 9 * 32 + qd * 8,
                 aA0, aB0, aC0, aA1, aB1, aC1)
      } else {
        xv[0]=xf0.x; xv[1]=xf0.y; xv[2]=xf0.z; xv[3]=xf0.w;
        xv[4]=xf1.x; xv[5]=xf1.y; xv[6]=xf1.z; xv[7]=xf1.w;
        splitv8(xv, xh, xl);
        MFMA_CH6(xh, xl, pB1h0, pB1l0, pB1h1, pB1l1, 10 * 32 + qd * 8,
                 aA0, aB0, aC0, aA1, aB1, aC1)
      }
    }

    // h1[t] terms -> BOTH layers (fragment reused for Wh1 and Wi2)
#pragma unroll
    for (int i = 0; i < 4; ++i) {
      bf16x8 fh = hi8(rwh1[i]), fl = lo8(rwh1[i]);
      const int koff = (kh * 4 + i) * 32 + qd * 8;
      if (doA)
        MFMA_CH6(fh, fl, pB1h0, pB1l0, pB1h1, pB1l1, koff, aA0, aB0, aC0, aA1, aB1, aC1)
      MFMA_CH6(fh, fl, pB2h0, pB2l0, pB2h1, pB2l1, koff, bA0, bB0, bC0, bA1, bB1, bC1)
    }
    // h2[t-1] terms (L2)
    if (t > 0) {
#pragma unroll
      for (int i = 0; i < 4; ++i) {
        bf16x8 fh = hi8(rw2[i]), fl = lo8(rw2[i]);
        const int koff = (8 + kh * 4 + i) * 32 + qd * 8;
        MFMA_CH6(fh, fl, pB2h0, pB2l0, pB2h1, pB2l1, koff, bA0, bB0, bC0, bA1, bB1, bC1)
      }
    }

    // ---- z exchange for both layers, one barrier ----
    f32x4 z2k = (kh == 0) ? (bA0 + bB0 + bC0) : (bA1 + bB1 + bC1);
    f32x4 z2o = (kh == 0) ? (bA1 + bB1 + bC1) : (bA0 + bB0 + bC0);
    *(f32x4*)&zx[0][wv][lane][0] = z2o;
    f32x4 z1k = {0,0,0,0};
    if (doA) {
      z1k = (kh == 0) ? (aA0 + aB0 + aC0) : (aA1 + aB1 + aC1);
      f32x4 z1o = (kh == 0) ? (aA1 + aB1 + aC1) : (aA0 + aB0 + aC0);
      *(f32x4*)&zx[1][wv][lane][0] = z1o;
    }
    __syncthreads();
    z2k += *(const f32x4*)&zx[0][wv ^ 4][lane][0];
    if (doA) {
      z1k += *(const f32x4*)&zx[1][wv ^ 4][lane][0];
      GATES_ST(z1k, cs1, h1nw)       // h1[t+1]
    }
    GATES_ST(z2k, cs2, h2cw)         // h2[t]
    post_flag(fCslot, (u32)(t + 2)); // single post: h1[t+1] + h2[t] published
  }

  // ---- dense head: logits = h2[511] @ Wd + bd (slot 1) ----
  wait_flags(fCp, TT + 1);
  if (tid < 2 * NC) {
    int r = row0 + jt * 2 + tid / NC;
    int n = tid - (tid / NC) * NC;
    float s = bd[n];
    const u32* fw = h2w + BBHH + (size_t)r * HH;
#pragma unroll 8
    for (int k = 0; k < HH; ++k) {
      u32 w = ald1(fw + k);
      s += (bf2f((u16)w) + bf2f((u16)(w >> 16))) * Wd[k * NC + n];
    }
    out[r * NC + n] = s;
  }
}

extern "C" void kernel_launch(void* const* d_in, const int* in_sizes, int n_in,
                              void* d_out, int out_size, void* d_ws, size_t ws_size,
                              hipStream_t stream) {
  const float* x   = (const float*)d_in[0];
  const float* Wi1 = (const float*)d_in[1];
  const float* Wh1 = (const float*)d_in[2];
  const float* b1  = (const float*)d_in[3];
  const float* Wi2 = (const float*)d_in[4];
  const float* Wh2 = (const float*)d_in[5];
  const float* b2  = (const float*)d_in[6];
  const float* Wd  = (const float*)d_in[7];
  const float* bd  = (const float*)d_in[8];

  char* ws = (char*)d_ws;
  // ws layout (bytes):
  //   [0, 1M)          h1w ping-pong u32 words (hi|lo<<16) [2][512][256]
  //   [1M, 2M)         h2w
  //   [2M, ..)         w1hg/w1lg (720,896 each), w2hg/w2lg (1,048,576 each)
  //   [5,636,096, +64K) fused flag array (zeroed every call)
  u32* h1w = (u32*)(ws);
  u32* h2w = (u32*)(ws + 1048576u);
  u16* w1hg = (u16*)(ws + 2097152u);
  u16* w1lg = (u16*)(ws + 2097152u + 720896u);
  u16* w2hg = (u16*)(ws + 2097152u + 2u * 720896u);
  u16* w2lg = (u16*)(ws + 2097152u + 2u * 720896u + 1048576u);
  u32* flags = (u32*)(ws + 5636096u);
  float* out = (float*)d_out;

  hipMemsetAsync((void*)flags, 0, 65536, stream);
  const int total = 1024 * K1 + 1024 * K2;
  repack_kernel<<<(total + 255) / 256, 256, 0, stream>>>(
      Wi1, Wh1, Wi2, Wh2, w1hg, w1lg, w2hg, w2lg);

  void* args[] = {
    (void*)&x, (void*)&b1, (void*)&b2, (void*)&Wd, (void*)&bd,
    (void*)&w1hg, (void*)&w1lg, (void*)&w2hg, (void*)&w2lg,
    (void*)&h1w, (void*)&h2w,
    (void*)&flags, (void*)&out
  };
  // Cooperative launch purely for the co-residency guarantee; sync is custom.
  (void)hipLaunchCooperativeKernel((void*)lstm_kernel, dim3(NBLK),
                                   dim3(NTHREADS), args, 0, stream);
}